// Round 7
// baseline (566.892 us; speedup 1.0000x reference)
//
#include <hip/hip_runtime.h>

typedef unsigned short u16;
typedef unsigned int   u32;
typedef __attribute__((ext_vector_type(8))) __bf16 bf16x8;
typedef __attribute__((ext_vector_type(4))) float  f32x4;

#define AS1 __attribute__((address_space(1)))
#define AS3 __attribute__((address_space(3)))

// B=4096, K=64, D=128, H=2048, V=10000, IN=8640
// Permuted inp layout per row: [0,128) u | [128,8320) v | [8320,8576) extras | [8576,8640) pop
// W1 rows permuted identically in transpose_w1.

__device__ __forceinline__ u16 f2bf(float f) {
  u32 u = __builtin_bit_cast(u32, f);
  u += 0x7fffu + ((u >> 16) & 1u);   // RNE
  return (u16)(u >> 16);
}

__device__ __forceinline__ float wred(float v) {
#pragma unroll
  for (int off = 32; off > 0; off >>= 1) v += __shfl_xor(v, off, 64);
  return v;
}

__device__ __forceinline__ void stage16(const u16* g, u16* l) {
  __builtin_amdgcn_global_load_lds((const AS1 void*)g, (AS3 void*)l, 16, 0, 0);
}

// ---------------- feature kernel ----------------
__global__ __launch_bounds__(256) void feature_kernel(
    const float* __restrict__ te, const int* __restrict__ nidx,
    const float* __restrict__ freq, const float* __restrict__ lut,
    u16* __restrict__ inp)
{
  const int b = blockIdx.x;
  const int t = threadIdx.x;
  const int l = t & 63, w = t >> 6;
  __shared__ float u_sh[128];
  __shared__ float squ_sh;

  if (t < 128) u_sh[t] = te[(size_t)b * 128 + t];
  __syncthreads();
  if (w == 0) {
    float p = u_sh[l] * u_sh[l] + u_sh[l + 64] * u_sh[l + 64];
    p = wred(p);
    if (l == 0) squ_sh = p;
  }
  const size_t rb = (size_t)b * 8640;
  if (t < 64) {
    float2 u2 = *(const float2*)&u_sh[t * 2];
    u32 pk = (u32)f2bf(u2.x) | ((u32)f2bf(u2.y) << 16);
    *(u32*)&inp[rb + t * 2] = pk;
  }
  __syncthreads();

  const float squ = squ_sh;
  const float2 u2 = *(const float2*)&u_sh[l * 2];
  for (int k = w; k < 64; k += 4) {
    const int idx = nidx[b * 64 + k];
    const float2 v2 = *(const float2*)&lut[(size_t)idx * 128 + l * 2];
    float sqv = v2.x * v2.x + v2.y * v2.y;
    float dot = u2.x * v2.x + u2.y * v2.y;
    float dx = u2.x - v2.x, dy = u2.y - v2.y;
    float sqd = dx * dx + dy * dy;
    float sx = u2.x + v2.x, sy = u2.y + v2.y;
    float ssm = sx * sx + sy * sy;
    sqv = wred(sqv); dot = wred(dot); sqd = wred(sqd); ssm = wred(ssm);

    u32 pk = (u32)f2bf(v2.x) | ((u32)f2bf(v2.y) << 16);
    *(u32*)&inp[rb + 128 + (size_t)k * 128 + l * 2] = pk;

    if (l == 0) {
      float x = 1.0f + 2.0f * sqd / ((1.0f - squ) * (1.0f - sqv));
      x = fmaxf(x, 1.0f + 1e-5f);
      float poin = logf(x + sqrtf(x * x - 1.0f));
      float cosv = dot / fmaxf(sqrtf(squ) * sqrtf(sqv), 1e-8f);
      float pol  = (ssm - sqd) * 0.25f;
      u32 p0 = (u32)f2bf(poin) | ((u32)f2bf(cosv) << 16);
      u32 p1 = (u32)f2bf(pol)  | ((u32)f2bf(dot)  << 16);
      *(u32*)&inp[rb + 8320 + k * 4]     = p0;
      *(u32*)&inp[rb + 8320 + k * 4 + 2] = p1;
      inp[rb + 8576 + k] = f2bf(log1pf(freq[idx]));
    }
  }
}

// -------- W1 transpose with feature permutation --------
__device__ __forceinline__ int w1_orig_row(int p) {
  if (p < 128) return p;
  if (p < 8320) { int q = p - 128;  return 128 + (q >> 7) * 133 + (q & 127); }
  if (p < 8576) { int q = p - 8320; return 128 + (q >> 2) * 133 + 128 + (q & 3); }
  return 128 + (p - 8576) * 133 + 132;
}

__global__ __launch_bounds__(256) void transpose_w1(
    const float* __restrict__ in, u16* __restrict__ out)
{
  __shared__ u16 ls[64][65];
  const int p0 = (blockIdx.x >> 5) << 6;
  const int h0 = (blockIdx.x & 31) << 6;
  const int t = threadIdx.x;
  const int hl = t & 63, q = t >> 6;
#pragma unroll
  for (int i = 0; i < 16; i++) {
    int pl = i * 4 + q;
    int orig = w1_orig_row(p0 + pl);
    ls[pl][hl] = f2bf(in[(size_t)orig * 2048 + h0 + hl]);
  }
  __syncthreads();
  const int pr = t & 63;
#pragma unroll
  for (int i = 0; i < 16; i++) {
    int hc = i * 4 + q;
    out[(size_t)(h0 + hc) * 8640 + p0 + pr] = ls[pr][hc];
  }
}

// -------- generic transpose+convert --------
__global__ __launch_bounds__(256) void transpose_conv(
    const float* __restrict__ in, u16* __restrict__ out, int R, int C)
{
  __shared__ u16 ls[64][65];
  const int tiles_c = C >> 6;
  const int r0 = (blockIdx.x / tiles_c) << 6;
  const int c0 = (blockIdx.x % tiles_c) << 6;
  const int t = threadIdx.x;
  const int cl = t & 63, q = t >> 6;
#pragma unroll
  for (int i = 0; i < 16; i++) {
    int rl = i * 4 + q;
    ls[rl][cl] = f2bf(in[(size_t)(r0 + rl) * C + c0 + cl]);
  }
  __syncthreads();
  const int rr = t & 63;
#pragma unroll
  for (int i = 0; i < 16; i++) {
    int cc = i * 4 + q;
    out[(size_t)(c0 + cc) * R + r0 + rr] = ls[rr][cc];
  }
}

// ======== gemm3b: C(M,N) = relu(A(M,Kd)*BT(N,Kd)^T + bias), out bf16 ========
// BM=128 BN=128 BK=64. 256 thr = 4 waves (2Mx2N), wave tile 64x64, acc[4][4].
// B fragments GLOBAL->REG (L2-hot; no LDS traffic for B). A via gload_lds
// into ring-3 x 16KB = 48KB LDS -> 2-3 blocks/CU resident: INTER-BLOCK TLP
// fills the LDS-wait gaps (R6 lesson: intra-block waves are symmetric and
// serialize; m114 overlap needs independent blocks). Ledger: loadB(ti) then
// stageA(ti+2); compiler's auto vmcnt(4) before MFMA (b-reg dep) transitively
// drains stageA(ti+1) (in-order vmcnt) while keeping stageA(ti+2) in flight.
// One vmcnt(4)+barrier per interval. T2 slot-XOR swizzle on A (0-conflict,
// R6-verified pattern).
__global__ __launch_bounds__(256, 3) void gemm3b(
    const u16* __restrict__ A, const u16* __restrict__ BT,
    const float* __restrict__ bias, u16* __restrict__ out,
    int N, int Kd)
{
  extern __shared__ u16 lds[];   // 3 * 8192 u16 = 48KB
  const int t = threadIdx.x, l = t & 63, w = t >> 6;
  const int nb = N >> 7;
  const int cpx = gridDim.x >> 3;
  const int bid = (blockIdx.x & 7) * cpx + (blockIdx.x >> 3);
  const int bm = bid / nb, bn = bid % nb;
  const int m0 = bm << 7, n0 = bn << 7;
  const int vm = w >> 1, vn = w & 1;

  const size_t lda = (size_t)Kd;
  const int NT = Kd >> 6;

  // stage consts: round r covers rows r*32+[0,32); lane row = w*8+(l>>3),
  // logical chunk q = (l&7)^(l>>3) -> phys chunk (l&7) after swizzle
  const u16* sA = A + (size_t)(m0 + w * 8 + (l >> 3)) * lda + (((l & 7) ^ (l >> 3)) * 8);
  const int dL = w * 512;   // u16; gload_lds adds lane*16B itself

  // B reg-load consts: col = n0+vn*64+ni*16+(l&15), k = kt+ks*32+(l>>4)*8
  const u16* pB = BT + (size_t)(n0 + vn * 64 + (l & 15)) * lda + (l >> 4) * 8;

  // A reader consts (swizzled): row = vm*64+mi*16+(l&15), chunk = (ks*4+(l>>4))^(l&7)
  const int aBase = (vm * 64 + (l & 15)) * 64;
  const int c0 = (((l >> 4)) ^ (l & 7)) * 8;
  const int c1 = ((4 + (l >> 4)) ^ (l & 7)) * 8;

  f32x4 acc[4][4] = {};
  bf16x8 af[8], b[8];

  auto stageT = [&](int o, int tt) {
    const size_t kt = (size_t)tt * 64;
    stage16(sA + kt,            lds + o + dL);
    stage16(sA + 32 * lda + kt, lds + o + 2048 + dL);
    stage16(sA + 64 * lda + kt, lds + o + 4096 + dL);
    stage16(sA + 96 * lda + kt, lds + o + 6144 + dL);
  };

  int o0 = 0, o1 = 8192, o2 = 16384;
  stageT(o0, 0);
  if (NT > 1) stageT(o1, 1);
  asm volatile("s_waitcnt vmcnt(4)" ::: "memory");
  __builtin_amdgcn_s_barrier();

  for (int ti = 0; ti < NT; ++ti) {
    const size_t kt = (size_t)ti * 64;
    // B fragments for THIS tile (L2 latency hidden by TLP + issue window)
#pragma unroll
    for (int ni = 0; ni < 4; ni++) {
      b[ni * 2 + 0] = *(const bf16x8*)(pB + (size_t)ni * 16 * lda + kt);
      b[ni * 2 + 1] = *(const bf16x8*)(pB + (size_t)ni * 16 * lda + kt + 32);
    }
    __builtin_amdgcn_sched_barrier(0);
    if (ti + 2 < NT) stageT(o2, ti + 2);
    __builtin_amdgcn_sched_barrier(0);
#pragma unroll
    for (int mi = 0; mi < 4; mi++) {
      af[mi * 2 + 0] = *(const bf16x8*)&lds[o0 + aBase + mi * 1024 + c0];
      af[mi * 2 + 1] = *(const bf16x8*)&lds[o0 + aBase + mi * 1024 + c1];
    }
    asm volatile("s_waitcnt lgkmcnt(0)" ::: "memory");
    __builtin_amdgcn_sched_barrier(0);
    __builtin_amdgcn_s_setprio(1);
#pragma unroll
    for (int ks = 0; ks < 2; ks++)
#pragma unroll
      for (int mi = 0; mi < 4; mi++)
#pragma unroll
        for (int ni = 0; ni < 4; ni++)
          acc[mi][ni] = __builtin_amdgcn_mfma_f32_16x16x32_bf16(
              af[mi * 2 + ks], b[ni * 2 + ks], acc[mi][ni], 0, 0, 0);
    __builtin_amdgcn_s_setprio(0);
    asm volatile("s_waitcnt vmcnt(4)" ::: "memory");  // ti+1 staged; ti+2 in flight
    __builtin_amdgcn_s_barrier();
    const int tmp = o0; o0 = o1; o1 = o2; o2 = tmp;
  }

  const int rq = l >> 4, rl2 = l & 15;
#pragma unroll
  for (int mi = 0; mi < 4; mi++) {
#pragma unroll
    for (int ni = 0; ni < 4; ni++) {
      const int col = n0 + vn * 64 + ni * 16 + rl2;
      const float bv = bias[col];
#pragma unroll
      for (int j = 0; j < 4; j++) {
        const int row = m0 + vm * 64 + mi * 16 + rq * 4 + j;
        float vv = acc[mi][ni][j] + bv;
        out[(size_t)row * N + col] = f2bf(fmaxf(vv, 0.0f));
      }
    }
  }
}

// -------- gemm4 split-K partial: 128 rows x 64 cols over K[k0,k0+512) --------
__global__ __launch_bounds__(256, 2) void gemm4_part(
    const u16* __restrict__ A, const u16* __restrict__ BT,
    float* __restrict__ pbuf)
{
  __shared__ u16 lsA[2 * 128 * 32];
  __shared__ u16 lsB[2 * 64 * 32];
  const int t = threadIdx.x, l = t & 63, w = t >> 6;
  const int bmx = blockIdx.x & 31, sk = blockIdx.x >> 5;
  const int m0 = bmx << 7, k0 = sk << 9;
  float* pout = pbuf + (size_t)sk * 262144;
  const int wm = w >> 1, wn = w & 1;

  f32x4 acc[4][2] = {};
  const int srow = l >> 2, scol = (l & 3) * 8;

  const u16* pA0 = A  + (size_t)(m0 + w * 16 + srow)      * 2048 + scol + k0;
  const u16* pA1 = A  + (size_t)(m0 + 64 + w * 16 + srow) * 2048 + scol + k0;
  const u16* pB0 = BT + (size_t)(w * 16 + srow)           * 2048 + scol + k0;

  auto stage = [&](int buf, int kt) {
    u16* dA = lsA + buf * 4096;
    u16* dB = lsB + buf * 2048;
    stage16(pA0 + kt, dA + w * 512);
    stage16(pA1 + kt, dA + 2048 + w * 512);
    stage16(pB0 + kt, dB + w * 512);
  };

  stage(0, 0);
  __syncthreads();

  const int kk = (l >> 4) * 8;
  const int rl = l & 15;
  int cur = 0;
  for (int kt = 0; kt < 512; kt += 32) {
    if (kt + 32 < 512) stage(cur ^ 1, kt + 32);
    const u16* sA = lsA + cur * 4096;
    const u16* sB = lsB + cur * 2048;
    bf16x8 a[4], bb[2];
#pragma unroll
    for (int mi = 0; mi < 4; mi++)
      a[mi] = *(const bf16x8*)&sA[(wm * 64 + mi * 16 + rl) * 32 + kk];
#pragma unroll
    for (int ni = 0; ni < 2; ni++)
      bb[ni] = *(const bf16x8*)&sB[(wn * 32 + ni * 16 + rl) * 32 + kk];
#pragma unroll
    for (int mi = 0; mi < 4; mi++)
#pragma unroll
      for (int ni = 0; ni < 2; ni++)
        acc[mi][ni] = __builtin_amdgcn_mfma_f32_16x16x32_bf16(a[mi], bb[ni], acc[mi][ni], 0, 0, 0);
    __syncthreads();
    cur ^= 1;
  }

  const int rq = l >> 4, rl2 = l & 15;
#pragma unroll
  for (int mi = 0; mi < 4; mi++)
#pragma unroll
    for (int ni = 0; ni < 2; ni++) {
      const int col = wn * 32 + ni * 16 + rl2;
#pragma unroll
      for (int j = 0; j < 4; j++) {
        const int row = m0 + wm * 64 + mi * 16 + rq * 4 + j;
        pout[(size_t)row * 64 + col] = acc[mi][ni][j];
      }
    }
}

// -------- combine: sum 4 partials + bias -> sigmoid + BCE partials --------
__global__ __launch_bounds__(256) void gemm4_combine(
    const float* __restrict__ pbuf, const float* __restrict__ bias,
    const float* __restrict__ oneh, float* __restrict__ dist,
    float* __restrict__ part2)
{
  __shared__ float red[256];
  const int t = threadIdx.x;
  const size_t base = (size_t)blockIdx.x * 1024 + t * 4;
  f32x4 s = *(const f32x4*)&pbuf[base];
  s += *(const f32x4*)&pbuf[base + 262144];
  s += *(const f32x4*)&pbuf[base + 524288];
  s += *(const f32x4*)&pbuf[base + 786432];
  const int col0 = (int)(base & 63);
  f32x4 th = *(const f32x4*)&oneh[base];
  float lsum = 0.0f;
  f32x4 dv;
#pragma unroll
  for (int j = 0; j < 4; j++) {
    const float x = s[j] + bias[col0 + j];
    dv[j] = 1.0f / (1.0f + expf(-x));
    lsum += fmaxf(x, 0.0f) - x * th[j] + log1pf(expf(-fabsf(x)));
  }
  *(f32x4*)&dist[base] = dv;
  red[t] = lsum;
  __syncthreads();
  for (int s2 = 128; s2 > 0; s2 >>= 1) {
    if (t < s2) red[t] += red[t + s2];
    __syncthreads();
  }
  if (t == 0) part2[blockIdx.x] = red[0];
}

__global__ void loss_final(const float* __restrict__ part2, float* __restrict__ outloss) {
  const int l = threadIdx.x;
  float v = 0.0f;
#pragma unroll
  for (int i = 0; i < 4; i++) v += part2[l + i * 64];
  v = wred(v);
  if (l == 0) outloss[0] = v * (1.0f / 262144.0f);
}

// ---------------- launch ----------------
extern "C" void kernel_launch(void* const* d_in, const int* in_sizes, int n_in,
                              void* d_out, int out_size, void* d_ws, size_t ws_size,
                              hipStream_t stream)
{
  const float* te   = (const float*)d_in[0];
  const int*   nidx = (const int*)  d_in[1];
  const float* oneh = (const float*)d_in[2];
  const float* freq = (const float*)d_in[3];
  const float* lut  = (const float*)d_in[4];
  const float* W1   = (const float*)d_in[5];
  const float* b1   = (const float*)d_in[6];
  const float* Wh1  = (const float*)d_in[7];
  const float* bh1  = (const float*)d_in[8];
  const float* Wh2  = (const float*)d_in[9];
  const float* bh2  = (const float*)d_in[10];
  const float* W2   = (const float*)d_in[11];
  const float* b2   = (const float*)d_in[12];

  float* dist  = (float*)d_out;          // 4096*64
  float* lossp = dist + 262144;          // +1

  size_t off = 0;
  char* base = (char*)d_ws;
  auto alloc = [&](size_t bytes) { char* p = base + off; off += (bytes + 255) & ~(size_t)255; return p; };
  u16* inp   = (u16*)alloc((size_t)4096 * 8640 * 2);
  u16* w1t   = (u16*)alloc((size_t)2048 * 8640 * 2);
  u16* wh1t  = (u16*)alloc((size_t)2048 * 2048 * 2);
  u16* wh2t  = (u16*)alloc((size_t)2048 * 2048 * 2);
  u16* w2t   = (u16*)alloc((size_t)64 * 2048 * 2);
  u16* h1    = (u16*)alloc((size_t)4096 * 2048 * 2);
  float* part2 = (float*)alloc(1024);
  u16* h2 = inp;                  // inp dead after GEMM1
  u16* h3 = w1t;                  // w1t dead after GEMM1
  float* pbuf = (float*)wh1t;     // wh1t dead after GEMM2; 4*4096*64*4B = 4MB < 8.4MB
  if (off > ws_size) return;

  (void)hipFuncSetAttribute((const void*)gemm3b,
                            hipFuncAttributeMaxDynamicSharedMemorySize, 49152);

  feature_kernel<<<4096, 256, 0, stream>>>(te, nidx, freq, lut, inp);
  transpose_w1 <<<135 * 32, 256, 0, stream>>>(W1, w1t);
  transpose_conv<<<32 * 32, 256, 0, stream>>>(Wh1, wh1t, 2048, 2048);
  transpose_conv<<<32 * 32, 256, 0, stream>>>(Wh2, wh2t, 2048, 2048);
  transpose_conv<<<32 * 1, 256, 0, stream>>>(W2, w2t, 2048, 64);

  gemm3b<<<512, 256, 49152, stream>>>(inp, w1t, b1, h1, 2048, 8640);
  gemm3b<<<512, 256, 49152, stream>>>(h1, wh1t, bh1, h2, 2048, 2048);
  gemm3b<<<512, 256, 49152, stream>>>(h2, wh2t, bh2, h3, 2048, 2048);
  gemm4_part   <<<128, 256, 0, stream>>>(h3, w2t, pbuf);
  gemm4_combine<<<256, 256, 0, stream>>>(pbuf, b2, oneh, dist, part2);
  loss_final   <<<1, 64, 0, stream>>>(part2, lossp);
}

// Round 8
// 335.581 us; speedup vs baseline: 1.6893x; 1.6893x over previous
//
#include <hip/hip_runtime.h>

typedef unsigned short u16;
typedef unsigned int   u32;
typedef __attribute__((ext_vector_type(8))) __bf16 bf16x8;
typedef __attribute__((ext_vector_type(4))) float  f32x4;
typedef __attribute__((ext_vector_type(4))) u32    u32x4;

#define AS1 __attribute__((address_space(1)))
#define AS3 __attribute__((address_space(3)))

// B=4096, K=64, D=128, H=2048, V=10000, IN=8640
// Permuted inp layout per row: [0,128) u | [128,8320) v | [8320,8576) extras | [8576,8640) pop
// W1 rows permuted identically in transpose_w1.

__device__ __forceinline__ u16 f2bf(float f) {
  u32 u = __builtin_bit_cast(u32, f);
  u += 0x7fffu + ((u >> 16) & 1u);   // RNE
  return (u16)(u >> 16);
}

__device__ __forceinline__ float wred(float v) {
#pragma unroll
  for (int off = 32; off > 0; off >>= 1) v += __shfl_xor(v, off, 64);
  return v;
}

__device__ __forceinline__ void stage16(const u16* g, u16* l) {
  __builtin_amdgcn_global_load_lds((const AS1 void*)g, (AS3 void*)l, 16, 0, 0);
}

// ---------------- feature kernel v2 ----------------
// identities: sqdist = squ + sqv - 2 dot ; polarization = dot.
// -> only 2 wave-reductions per k (sqv, dot); 4 k's per macro-iter with
// interleaved butterflies; extras computed on ALL lanes (butterfly
// broadcasts), lane 0 stores 2x16B extras + 8B pop per macro-iter.
__global__ __launch_bounds__(256) void feature_kernel(
    const float* __restrict__ te, const int* __restrict__ nidx,
    const float* __restrict__ freq, const float* __restrict__ lut,
    u16* __restrict__ inp)
{
  const int b = blockIdx.x;
  const int t = threadIdx.x;
  const int l = t & 63, w = t >> 6;
  __shared__ float u_sh[128];
  __shared__ float squ_sh;

  if (t < 128) u_sh[t] = te[(size_t)b * 128 + t];
  __syncthreads();
  if (w == 0) {
    float p = u_sh[l] * u_sh[l] + u_sh[l + 64] * u_sh[l + 64];
    p = wred(p);
    if (l == 0) squ_sh = p;
  }
  const size_t rb = (size_t)b * 8640;
  if (t < 64) {
    float2 u2 = *(const float2*)&u_sh[t * 2];
    u32 pk = (u32)f2bf(u2.x) | ((u32)f2bf(u2.y) << 16);
    *(u32*)&inp[rb + t * 2] = pk;
  }
  __syncthreads();

  const float squ = squ_sh;
  const float rsq = 1.0f - squ;
  const float2 u2 = *(const float2*)&u_sh[l * 2];

#pragma unroll
  for (int mk = 0; mk < 4; ++mk) {
    const int kbase = w * 16 + mk * 4;
    int idx[4]; float2 v2[4]; float sqv[4], dot[4];
#pragma unroll
    for (int j = 0; j < 4; j++) {
      idx[j] = nidx[b * 64 + kbase + j];
      v2[j] = *(const float2*)&lut[(size_t)idx[j] * 128 + l * 2];
    }
#pragma unroll
    for (int j = 0; j < 4; j++) {
      sqv[j] = v2[j].x * v2[j].x + v2[j].y * v2[j].y;
      dot[j] = u2.x * v2[j].x + u2.y * v2[j].y;
    }
#pragma unroll
    for (int off = 32; off > 0; off >>= 1) {
#pragma unroll
      for (int j = 0; j < 4; j++) {
        sqv[j] += __shfl_xor(sqv[j], off, 64);
        dot[j] += __shfl_xor(dot[j], off, 64);
      }
    }
#pragma unroll
    for (int j = 0; j < 4; j++) {
      u32 pk = (u32)f2bf(v2[j].x) | ((u32)f2bf(v2[j].y) << 16);
      *(u32*)&inp[rb + 128 + (size_t)(kbase + j) * 128 + l * 2] = pk;
    }
    float poin[4], cosv[4];
#pragma unroll
    for (int j = 0; j < 4; j++) {
      const float sqd = squ + sqv[j] - 2.0f * dot[j];
      float x = 1.0f + 2.0f * sqd / (rsq * (1.0f - sqv[j]));
      x = fmaxf(x, 1.0f + 1e-5f);
      poin[j] = logf(x + sqrtf(x * x - 1.0f));
      cosv[j] = dot[j] / fmaxf(sqrtf(squ * sqv[j]), 1e-8f);
    }
    if (l == 0) {
      u32x4 e0, e1;
#pragma unroll
      for (int j = 0; j < 2; j++) {
        e0[2 * j]     = (u32)f2bf(poin[j]) | ((u32)f2bf(cosv[j]) << 16);
        e0[2 * j + 1] = (u32)f2bf(dot[j])  | ((u32)f2bf(dot[j])  << 16);
        e1[2 * j]     = (u32)f2bf(poin[2 + j]) | ((u32)f2bf(cosv[2 + j]) << 16);
        e1[2 * j + 1] = (u32)f2bf(dot[2 + j])  | ((u32)f2bf(dot[2 + j])  << 16);
      }
      *(u32x4*)&inp[rb + 8320 + kbase * 4]     = e0;
      *(u32x4*)&inp[rb + 8320 + kbase * 4 + 8] = e1;
      u16 pp[4];
#pragma unroll
      for (int j = 0; j < 4; j++) pp[j] = f2bf(log1pf(freq[idx[j]]));
      *(u32*)&inp[rb + 8576 + kbase]     = (u32)pp[0] | ((u32)pp[1] << 16);
      *(u32*)&inp[rb + 8576 + kbase + 2] = (u32)pp[2] | ((u32)pp[3] << 16);
    }
  }
}

// -------- W1 transpose with feature permutation --------
__device__ __forceinline__ int w1_orig_row(int p) {
  if (p < 128) return p;
  if (p < 8320) { int q = p - 128;  return 128 + (q >> 7) * 133 + (q & 127); }
  if (p < 8576) { int q = p - 8320; return 128 + (q >> 2) * 133 + 128 + (q & 3); }
  return 128 + (p - 8576) * 133 + 132;
}

// LDS tile stored [h][p] stride 68 (writes 2-lanes/bank = free; reads
// 8B-aligned, <=4-way). Output stores vectorized to 8B/lane.
__global__ __launch_bounds__(256) void transpose_w1(
    const float* __restrict__ in, u16* __restrict__ out)
{
  __shared__ u16 ls[64][68];
  const int p0 = (blockIdx.x >> 5) << 6;   // 135 p-tiles
  const int h0 = (blockIdx.x & 31) << 6;   // 32 h-tiles
  const int t = threadIdx.x;
  const int hl = t & 63, q = t >> 6;
#pragma unroll
  for (int i = 0; i < 16; i++) {
    int pl = i * 4 + q;
    int orig = w1_orig_row(p0 + pl);
    ls[hl][pl] = f2bf(in[(size_t)orig * 2048 + h0 + hl]);
  }
  __syncthreads();
  const int pp = t & 15, hq = t >> 4;      // 4B-groups of p, 16 h-rows/pass
#pragma unroll
  for (int i = 0; i < 4; i++) {
    int hc = i * 16 + hq;
    uint2 vv = *(const uint2*)&ls[hc][pp * 4];
    *(uint2*)&out[(size_t)(h0 + hc) * 8640 + p0 + pp * 4] = vv;
  }
}

// -------- generic transpose+convert --------
__global__ __launch_bounds__(256) void transpose_conv(
    const float* __restrict__ in, u16* __restrict__ out, int R, int C)
{
  __shared__ u16 ls[64][68];
  const int tiles_c = C >> 6;
  const int r0 = (blockIdx.x / tiles_c) << 6;
  const int c0 = (blockIdx.x % tiles_c) << 6;
  const int t = threadIdx.x;
  const int cl = t & 63, q = t >> 6;
#pragma unroll
  for (int i = 0; i < 16; i++) {
    int rl = i * 4 + q;
    ls[cl][rl] = f2bf(in[(size_t)(r0 + rl) * C + c0 + cl]);
  }
  __syncthreads();
  const int pp = t & 15, cq = t >> 4;
#pragma unroll
  for (int i = 0; i < 4; i++) {
    int cc = i * 16 + cq;
    uint2 vv = *(const uint2*)&ls[cc][pp * 4];
    *(uint2*)&out[(size_t)(c0 + cc) * R + r0 + pp * 4] = vv;
  }
}

// ======== gemm8p (R6-verified): C = relu(A(M,Kd)*BT(N,Kd)^T + bias) ========
// BM=256 BN=128 BK=64. 8 waves = 2 K-subgroups x (2Mx2N); wave tile 128x64.
// ONE barrier per interval; stage(ti+2) -> 12 ds_reads -> lgkm(4) -> 16 MFMA
// -> lgkm(0) -> 16 MFMA -> vmcnt(6) -> barrier. T2 slot-XOR swizzle, counted
// vmcnt (T4), setprio (T5). Ring-3 x 48KB LDS.
__global__ __launch_bounds__(512, 2) void gemm8p(
    const u16* __restrict__ A, const u16* __restrict__ BT,
    const float* __restrict__ bias, u16* __restrict__ out,
    int N, int Kd)
{
  extern __shared__ u16 lds[];   // 3 * 24576 u16 = 144KB
  const int t = threadIdx.x, l = t & 63, w = t >> 6;
  const int nb = N >> 7;
  const int cpx = gridDim.x >> 3;
  const int bid = (blockIdx.x & 7) * cpx + (blockIdx.x >> 3);
  const int bm = bid / nb, bn = bid % nb;
  const int m0 = bm << 8, n0 = bn << 7;

  const int kg = w >> 2;
  const int p  = w & 3;
  const int vm = p >> 1, vn = p & 1;

  const size_t lda = (size_t)Kd;
  const int NT = Kd >> 6;

  const int sr = l >> 3;
  const int q  = (l & 7) ^ (sr & 7);
  const u16* sA = A  + (size_t)(m0 + w * 8 + sr) * lda + q * 8;
  const u16* sB = BT + (size_t)(n0 + w * 8 + sr) * lda + q * 8;
  const int dL = w * 512 + l * 8;

  const int rl  = l & 15;
  const int swz = ((kg * 4 + (l >> 4)) ^ (l & 7)) * 8;
  const int aOff = (vm * 128 + rl) * 64 + swz;
  const int bOff = 16384 + (vn * 64 + rl) * 64 + swz;

  f32x4 acc[8][4] = {};
  bf16x8 af0[4], af1[4], bfr[4];

  auto stageT = [&](int o, int tt) {
    const size_t kt = (size_t)tt * 64;
    stage16(sA + kt,             lds + o + dL);
    stage16(sA + 64 * lda + kt,  lds + o + 4096 + dL);
    stage16(sA + 128 * lda + kt, lds + o + 8192 + dL);
    stage16(sA + 192 * lda + kt, lds + o + 12288 + dL);
    stage16(sB + kt,             lds + o + 16384 + dL);
    stage16(sB + 64 * lda + kt,  lds + o + 20480 + dL);
  };
  auto rdB = [&](int o) {
#pragma unroll
    for (int ni = 0; ni < 4; ni++)
      bfr[ni] = *(const bf16x8*)&lds[o + bOff + ni * 1024];
  };
  auto rdA0 = [&](int o) {
#pragma unroll
    for (int mi = 0; mi < 4; mi++)
      af0[mi] = *(const bf16x8*)&lds[o + aOff + mi * 1024];
  };
  auto rdA1 = [&](int o) {
#pragma unroll
    for (int mi = 0; mi < 4; mi++)
      af1[mi] = *(const bf16x8*)&lds[o + aOff + (4 + mi) * 1024];
  };
  auto mmq = [&](const bf16x8* a, int half) {
    __builtin_amdgcn_s_setprio(1);
#pragma unroll
    for (int mi = 0; mi < 4; mi++)
#pragma unroll
      for (int ni = 0; ni < 4; ni++)
        acc[half * 4 + mi][ni] =
            __builtin_amdgcn_mfma_f32_16x16x32_bf16(a[mi], bfr[ni], acc[half * 4 + mi][ni], 0, 0, 0);
    __builtin_amdgcn_s_setprio(0);
  };

  int o0 = 0, o1 = 24576, o2 = 49152;
  stageT(o0, 0);
  if (NT > 1) {
    stageT(o1, 1);
    asm volatile("s_waitcnt vmcnt(6)" ::: "memory");
  } else {
    asm volatile("s_waitcnt vmcnt(0)" ::: "memory");
  }
  __builtin_amdgcn_s_barrier();

  for (int ti = 0; ti < NT; ++ti) {
    const bool st = (ti + 2 < NT);
    if (st) stageT(o2, ti + 2);
    rdB(o0); rdA0(o0); rdA1(o0);
    asm volatile("s_waitcnt lgkmcnt(4)" ::: "memory");
    __builtin_amdgcn_sched_barrier(0);
    mmq(af0, 0);
    asm volatile("s_waitcnt lgkmcnt(0)" ::: "memory");
    __builtin_amdgcn_sched_barrier(0);
    mmq(af1, 1);
    if (st) asm volatile("s_waitcnt vmcnt(6)" ::: "memory");
    else    asm volatile("s_waitcnt vmcnt(0)" ::: "memory");
    __builtin_amdgcn_s_barrier();
    const int tmp = o0; o0 = o1; o1 = o2; o2 = tmp;
  }

  __syncthreads();
  float* pl = (float*)lds;
  if (kg == 1) {
#pragma unroll
    for (int mi = 0; mi < 8; mi++)
#pragma unroll
      for (int ni = 0; ni < 4; ni++)
        *(f32x4*)&pl[p * 8192 + (mi * 4 + ni) * 256 + l * 4] = acc[mi][ni];
  }
  __syncthreads();
  if (kg == 0) {
    const int rq = l >> 4, rl2 = l & 15;
#pragma unroll
    for (int mi = 0; mi < 8; mi++) {
#pragma unroll
      for (int ni = 0; ni < 4; ni++) {
        f32x4 p2 = *(const f32x4*)&pl[p * 8192 + (mi * 4 + ni) * 256 + l * 4];
        const int col = n0 + vn * 64 + ni * 16 + rl2;
        const float bv = bias[col];
#pragma unroll
        for (int j = 0; j < 4; j++) {
          const int row = m0 + vm * 128 + mi * 16 + rq * 4 + j;
          float vv = acc[mi][ni][j] + p2[j] + bv;
          out[(size_t)row * N + col] = f2bf(fmaxf(vv, 0.0f));
        }
      }
    }
  }
}

// -------- gemm4 split-K partial: 128 rows x 64 cols over K[k0,k0+512) --------
__global__ __launch_bounds__(256, 2) void gemm4_part(
    const u16* __restrict__ A, const u16* __restrict__ BT,
    float* __restrict__ pbuf)
{
  __shared__ u16 lsA[2 * 128 * 32];
  __shared__ u16 lsB[2 * 64 * 32];
  const int t = threadIdx.x, l = t & 63, w = t >> 6;
  const int bmx = blockIdx.x & 31, sk = blockIdx.x >> 5;
  const int m0 = bmx << 7, k0 = sk << 9;
  float* pout = pbuf + (size_t)sk * 262144;
  const int wm = w >> 1, wn = w & 1;

  f32x4 acc[4][2] = {};
  const int srow = l >> 2, scol = (l & 3) * 8;

  const u16* pA0 = A  + (size_t)(m0 + w * 16 + srow)      * 2048 + scol + k0;
  const u16* pA1 = A  + (size_t)(m0 + 64 + w * 16 + srow) * 2048 + scol + k0;
  const u16* pB0 = BT + (size_t)(w * 16 + srow)           * 2048 + scol + k0;

  auto stage = [&](int buf, int kt) {
    u16* dA = lsA + buf * 4096;
    u16* dB = lsB + buf * 2048;
    stage16(pA0 + kt, dA + w * 512);
    stage16(pA1 + kt, dA + 2048 + w * 512);
    stage16(pB0 + kt, dB + w * 512);
  };

  stage(0, 0);
  __syncthreads();

  const int kk = (l >> 4) * 8;
  const int rl = l & 15;
  int cur = 0;
  for (int kt = 0; kt < 512; kt += 32) {
    if (kt + 32 < 512) stage(cur ^ 1, kt + 32);
    const u16* sA = lsA + cur * 4096;
    const u16* sB = lsB + cur * 2048;
    bf16x8 a[4], bb[2];
#pragma unroll
    for (int mi = 0; mi < 4; mi++)
      a[mi] = *(const bf16x8*)&sA[(wm * 64 + mi * 16 + rl) * 32 + kk];
#pragma unroll
    for (int ni = 0; ni < 2; ni++)
      bb[ni] = *(const bf16x8*)&sB[(wn * 32 + ni * 16 + rl) * 32 + kk];
#pragma unroll
    for (int mi = 0; mi < 4; mi++)
#pragma unroll
      for (int ni = 0; ni < 2; ni++)
        acc[mi][ni] = __builtin_amdgcn_mfma_f32_16x16x32_bf16(a[mi], bb[ni], acc[mi][ni], 0, 0, 0);
    __syncthreads();
    cur ^= 1;
  }

  const int rq = l >> 4, rl2 = l & 15;
#pragma unroll
  for (int mi = 0; mi < 4; mi++)
#pragma unroll
    for (int ni = 0; ni < 2; ni++) {
      const int col = wn * 32 + ni * 16 + rl2;
#pragma unroll
      for (int j = 0; j < 4; j++) {
        const int row = m0 + wm * 64 + mi * 16 + rq * 4 + j;
        pout[(size_t)row * 64 + col] = acc[mi][ni][j];
      }
    }
}

// -------- combine: sum 4 partials + bias -> sigmoid + BCE partials --------
__global__ __launch_bounds__(256) void gemm4_combine(
    const float* __restrict__ pbuf, const float* __restrict__ bias,
    const float* __restrict__ oneh, float* __restrict__ dist,
    float* __restrict__ part2)
{
  __shared__ float red[256];
  const int t = threadIdx.x;
  const size_t base = (size_t)blockIdx.x * 1024 + t * 4;
  f32x4 s = *(const f32x4*)&pbuf[base];
  s += *(const f32x4*)&pbuf[base + 262144];
  s += *(const f32x4*)&pbuf[base + 524288];
  s += *(const f32x4*)&pbuf[base + 786432];
  const int col0 = (int)(base & 63);
  f32x4 th = *(const f32x4*)&oneh[base];
  float lsum = 0.0f;
  f32x4 dv;
#pragma unroll
  for (int j = 0; j < 4; j++) {
    const float x = s[j] + bias[col0 + j];
    dv[j] = 1.0f / (1.0f + expf(-x));
    lsum += fmaxf(x, 0.0f) - x * th[j] + log1pf(expf(-fabsf(x)));
  }
  *(f32x4*)&dist[base] = dv;
  red[t] = lsum;
  __syncthreads();
  for (int s2 = 128; s2 > 0; s2 >>= 1) {
    if (t < s2) red[t] += red[t + s2];
    __syncthreads();
  }
  if (t == 0) part2[blockIdx.x] = red[0];
}

__global__ void loss_final(const float* __restrict__ part2, float* __restrict__ outloss) {
  const int l = threadIdx.x;
  float v = 0.0f;
#pragma unroll
  for (int i = 0; i < 4; i++) v += part2[l + i * 64];
  v = wred(v);
  if (l == 0) outloss[0] = v * (1.0f / 262144.0f);
}

// ---------------- launch ----------------
extern "C" void kernel_launch(void* const* d_in, const int* in_sizes, int n_in,
                              void* d_out, int out_size, void* d_ws, size_t ws_size,
                              hipStream_t stream)
{
  const float* te   = (const float*)d_in[0];
  const int*   nidx = (const int*)  d_in[1];
  const float* oneh = (const float*)d_in[2];
  const float* freq = (const float*)d_in[3];
  const float* lut  = (const float*)d_in[4];
  const float* W1   = (const float*)d_in[5];
  const float* b1   = (const float*)d_in[6];
  const float* Wh1  = (const float*)d_in[7];
  const float* bh1  = (const float*)d_in[8];
  const float* Wh2  = (const float*)d_in[9];
  const float* bh2  = (const float*)d_in[10];
  const float* W2   = (const float*)d_in[11];
  const float* b2   = (const float*)d_in[12];

  float* dist  = (float*)d_out;          // 4096*64
  float* lossp = dist + 262144;          // +1

  size_t off = 0;
  char* base = (char*)d_ws;
  auto alloc = [&](size_t bytes) { char* p = base + off; off += (bytes + 255) & ~(size_t)255; return p; };
  u16* inp   = (u16*)alloc((size_t)4096 * 8640 * 2);
  u16* w1t   = (u16*)alloc((size_t)2048 * 8640 * 2);
  u16* wh1t  = (u16*)alloc((size_t)2048 * 2048 * 2);
  u16* wh2t  = (u16*)alloc((size_t)2048 * 2048 * 2);
  u16* w2t   = (u16*)alloc((size_t)64 * 2048 * 2);
  u16* h1    = (u16*)alloc((size_t)4096 * 2048 * 2);
  float* part2 = (float*)alloc(1024);
  u16* h2 = inp;                  // inp dead after GEMM1
  u16* h3 = w1t;                  // w1t dead after GEMM1
  float* pbuf = (float*)wh1t;     // wh1t dead after GEMM2; 4MB < 8.4MB
  if (off > ws_size) return;

  (void)hipFuncSetAttribute((const void*)gemm8p,
                            hipFuncAttributeMaxDynamicSharedMemorySize, 147456);

  feature_kernel<<<4096, 256, 0, stream>>>(te, nidx, freq, lut, inp);
  transpose_w1 <<<135 * 32, 256, 0, stream>>>(W1, w1t);
  transpose_conv<<<32 * 32, 256, 0, stream>>>(Wh1, wh1t, 2048, 2048);
  transpose_conv<<<32 * 32, 256, 0, stream>>>(Wh2, wh2t, 2048, 2048);
  transpose_conv<<<32 * 1, 256, 0, stream>>>(W2, w2t, 2048, 64);

  gemm8p<<<256, 512, 147456, stream>>>(inp, w1t, b1, h1, 2048, 8640);
  gemm8p<<<256, 512, 147456, stream>>>(h1, wh1t, bh1, h2, 2048, 2048);
  gemm8p<<<256, 512, 147456, stream>>>(h2, wh2t, bh2, h3, 2048, 2048);
  gemm4_part   <<<128, 256, 0, stream>>>(h3, w2t, pbuf);
  gemm4_combine<<<256, 256, 0, stream>>>(pbuf, b2, oneh, dist, part2);
  loss_final   <<<1, 64, 0, stream>>>(part2, lossp);
}